// Round 3
// baseline (6069.904 us; speedup 1.0000x reference)
//
#include <hip/hip_runtime.h>
#include <math.h>

#define BSZ 2048
#define DIM 2048
#define MS 6
#define NIT 29          // k = 1..29
#define LAMREG 1e-4f
#define XROWS (MS*DIM)  // 12288: row stride of the (bsz, 6, d) layouts

typedef __bf16 bf16x8 __attribute__((ext_vector_type(8)));
typedef float  f32x4  __attribute__((ext_vector_type(4)));

__device__ __forceinline__ void async16(const void* g, void* l) {
    __builtin_amdgcn_global_load_lds((const __attribute__((address_space(1))) void*)g,
                                     (__attribute__((address_space(3))) void*)l, 16, 0, 0);
}

// ---------------------------------------------------------------------------
// init: X[:,0] = x0, split-bf16 copy of x0, zero norms + dots
// ---------------------------------------------------------------------------
__global__ __launch_bounds__(256) void init_kernel(const float* __restrict__ x0,
                                                   float* __restrict__ Xout,
                                                   __bf16* __restrict__ Ahi,
                                                   __bf16* __restrict__ Alo,
                                                   float* __restrict__ norms,
                                                   float* __restrict__ dots) {
    int idx = blockIdx.x * 256 + threadIdx.x;
    if (idx < 2 * NIT) norms[idx] = 0.0f;
    if (idx < BSZ * MS) dots[idx] = 0.0f;
    for (int i = idx; i < BSZ * DIM; i += gridDim.x * 256) {
        int b = i >> 11;
        int j = i & (DIM - 1);
        float v = x0[i];
        Xout[(size_t)b * XROWS + j] = v;
        __bf16 h = (__bf16)v;
        Ahi[i] = h;
        Alo[i] = (__bf16)(v - (float)h);
    }
}

// ---------------------------------------------------------------------------
// W (K x N, f32) -> W^T split into bf16 hi/lo:  WT[n][k] = W[k][n]
// ---------------------------------------------------------------------------
__global__ __launch_bounds__(256) void wt_split_kernel(const float* __restrict__ W,
                                                       __bf16* __restrict__ WThi,
                                                       __bf16* __restrict__ WTlo) {
    __shared__ float tile[32][33];
    const int tx = threadIdx.x & 31;
    const int ty = threadIdx.x >> 5;
    const int n0 = blockIdx.x * 32;
    const int k0 = blockIdx.y * 32;
#pragma unroll
    for (int i = 0; i < 32; i += 8)
        tile[ty + i][tx] = W[(size_t)(k0 + ty + i) * DIM + n0 + tx];
    __syncthreads();
#pragma unroll
    for (int i = 0; i < 32; i += 8) {
        float v = tile[tx][ty + i];
        __bf16 h = (__bf16)v;
        size_t o = (size_t)(n0 + ty + i) * DIM + k0 + tx;
        WThi[o] = h;
        WTlo[o] = (__bf16)(v - (float)h);
    }
}

// ---------------------------------------------------------------------------
// split-bf16 MFMA GEMM, double-buffered LDS, fused epilogue:
//   F[:,up] = tanh(xnew @ W + b); g = F_up - X_up
//   dots[b,j] += sum_d g * (F_j - X_j)   (per-batch Gram row update)
//   optional global ||g||^2, ||f||^2 for the traces
// ---------------------------------------------------------------------------
__global__ __launch_bounds__(256) void gemm_mfma_kernel(
    const __bf16* __restrict__ Ahi, const __bf16* __restrict__ Alo,
    const __bf16* __restrict__ WThi, const __bf16* __restrict__ WTlo,
    const float* __restrict__ bias,
    float* __restrict__ Fbase, const float* __restrict__ Xbase,
    int up, int nact,
    float* __restrict__ dots, float* __restrict__ normAcc, int doNorm)
{
    __shared__ __align__(16) __bf16 Ah[2][128 * 32];
    __shared__ __align__(16) __bf16 Al[2][128 * 32];
    __shared__ __align__(16) __bf16 Bh[2][128 * 32];
    __shared__ __align__(16) __bf16 Bl[2][128 * 32];
    __shared__ float rs[8];

    const int tid = threadIdx.x;
    const int l = tid & 63;
    const int w = tid >> 6;
    const int m0 = blockIdx.y * 128;
    const int n0 = blockIdx.x * 128;
    const int wm = (w & 1) * 64;
    const int wn = (w >> 1) * 64;
    const int rl = l & 15;
    const int quad = l >> 4;
    const int kq = quad * 8;

    // staging: lane l of wave w loads 16B; HW scatters to ldsbase + l*16
    const int srow = w * 16 + (l >> 2);
    const int scol = (l & 3) * 8;
    const size_t aoff = (size_t)(m0 + srow) * DIM + scol;
    const size_t boff = (size_t)(n0 + srow) * DIM + scol;
    const int lo = w * 512;   // wave's element offset into each LDS panel

    f32x4 acc[4][4];
#pragma unroll
    for (int t = 0; t < 4; t++)
#pragma unroll
        for (int u = 0; u < 4; u++) acc[t][u] = (f32x4){0.f, 0.f, 0.f, 0.f};

    auto stage = [&](int kb, int s) {
        async16(Ahi + aoff + kb, &Ah[s][lo]);
        async16(Ahi + aoff + (size_t)64 * DIM + kb, &Ah[s][lo + 2048]);
        async16(Alo + aoff + kb, &Al[s][lo]);
        async16(Alo + aoff + (size_t)64 * DIM + kb, &Al[s][lo + 2048]);
        async16(WThi + boff + kb, &Bh[s][lo]);
        async16(WThi + boff + (size_t)64 * DIM + kb, &Bh[s][lo + 2048]);
        async16(WTlo + boff + kb, &Bl[s][lo]);
        async16(WTlo + boff + (size_t)64 * DIM + kb, &Bl[s][lo + 2048]);
    };
    auto compute = [&](int s) {
        bf16x8 ah[4], al[4];
#pragma unroll
        for (int t = 0; t < 4; t++) {
            const int ro = (wm + t * 16 + rl) * 32 + kq;
            ah[t] = *(const bf16x8*)&Ah[s][ro];
            al[t] = *(const bf16x8*)&Al[s][ro];
        }
#pragma unroll
        for (int u = 0; u < 4; u++) {
            const int co = (wn + u * 16 + rl) * 32 + kq;
            bf16x8 bh = *(const bf16x8*)&Bh[s][co];
            bf16x8 bl = *(const bf16x8*)&Bl[s][co];
#pragma unroll
            for (int t = 0; t < 4; t++) {
                acc[t][u] = __builtin_amdgcn_mfma_f32_16x16x32_bf16(ah[t], bh, acc[t][u], 0, 0, 0);
                acc[t][u] = __builtin_amdgcn_mfma_f32_16x16x32_bf16(al[t], bh, acc[t][u], 0, 0, 0);
                acc[t][u] = __builtin_amdgcn_mfma_f32_16x16x32_bf16(ah[t], bl, acc[t][u], 0, 0, 0);
            }
        }
    };

    stage(0, 0);                           // prologue prefetch
    for (int k0 = 0; k0 < DIM; k0 += 64) {
        __syncthreads();                   // drains buf0 prefetch (issued a full compute-phase ago)
        stage(k0 + 32, 1);                 // prefetch next while computing current
        compute(0);
        __syncthreads();                   // drains buf1 prefetch
        if (k0 + 64 < DIM) stage(k0 + 64, 0);
        compute(1);
    }

    // -------------------- epilogue --------------------
    int cols[4]; float bv[4];
#pragma unroll
    for (int u = 0; u < 4; u++) {
        cols[u] = n0 + wn + u * 16 + rl;
        bv[u] = bias[cols[u]];
    }
    float s1 = 0.0f, s2 = 0.0f;
#pragma unroll
    for (int t = 0; t < 4; t++) {
#pragma unroll
        for (int r = 0; r < 4; r++) {
            const int b = m0 + wm + t * 16 + quad * 4 + r;
            const size_t rowbase = (size_t)b * XROWS;
            float gu[4];
#pragma unroll
            for (int u = 0; u < 4; u++) {
                float v = tanhf(acc[t][u][r] + bv[u]);
                Fbase[rowbase + (size_t)up * DIM + cols[u]] = v;
                float xv = Xbase[rowbase + (size_t)up * DIM + cols[u]];
                float g = v - xv;
                gu[u] = g;
                if (doNorm) { s1 = fmaf(g, g, s1); s2 = fmaf(v, v, s2); }
            }
            for (int j = 0; j < nact; j++) {
                float p = 0.0f;
                if (j == up) {
#pragma unroll
                    for (int u = 0; u < 4; u++) p = fmaf(gu[u], gu[u], p);
                } else {
#pragma unroll
                    for (int u = 0; u < 4; u++) {
                        float fj = Fbase[rowbase + (size_t)j * DIM + cols[u]];
                        float xj = Xbase[rowbase + (size_t)j * DIM + cols[u]];
                        p = fmaf(gu[u], fj - xj, p);
                    }
                }
                // reduce across the 16 rl-lanes of this quad (same batch row)
                p += __shfl_xor(p, 1);
                p += __shfl_xor(p, 2);
                p += __shfl_xor(p, 4);
                p += __shfl_xor(p, 8);
                if (rl == 0) atomicAdd(&dots[(size_t)b * MS + j], p);
            }
        }
    }
    if (doNorm) {
#pragma unroll
        for (int off = 32; off > 0; off >>= 1) {
            s1 += __shfl_down(s1, off);
            s2 += __shfl_down(s2, off);
        }
        if (l == 0) { rs[w * 2] = s1; rs[w * 2 + 1] = s2; }
        __syncthreads();
        if (tid == 0) {
            atomicAdd(&normAcc[0], rs[0] + rs[2] + rs[4] + rs[6]);
            atomicAdd(&normAcc[1], rs[1] + rs[3] + rs[5] + rs[7]);
        }
    }
}

// ---------------------------------------------------------------------------
// per-batch: fold dots into persistent GGt (row/col prevUp), then solve the
// bordered (n+1) system -> alpha. One thread per batch row, H in LDS.
// ---------------------------------------------------------------------------
__global__ __launch_bounds__(256) void solve_kernel(
    float* __restrict__ GGt, const float* __restrict__ dots,
    float* __restrict__ alpha, int n, int prevUp)
{
    __shared__ float Hsh[256][7][8];
    const int b = blockIdx.x * 256 + threadIdx.x;
    if (b >= BSZ) return;
    float (*H)[8] = Hsh[threadIdx.x];
    float* gg = GGt + (size_t)b * 36;
    const float* dt = dots + (size_t)b * MS;
    for (int j = 0; j < n; j++) {
        float v = dt[j];
        gg[prevUp * 6 + j] = v;
        gg[j * 6 + prevUp] = v;
    }
    const int np = n + 1;
    for (int i = 0; i < np; i++) {
        for (int j = 0; j < np; j++) {
            float v;
            if (i == 0 && j == 0) v = 0.0f;
            else if (i == 0 || j == 0) v = 1.0f;
            else {
                v = gg[(i - 1) * 6 + (j - 1)];
                if (i == j) v += LAMREG;
            }
            H[i][j] = v;
        }
        H[i][7] = (i == 0) ? 1.0f : 0.0f;
    }
    // LU with partial pivoting
    for (int c = 0; c < np; c++) {
        int piv = c;
        float mx = fabsf(H[c][c]);
        for (int r = c + 1; r < np; r++) {
            float a = fabsf(H[r][c]);
            if (a > mx) { mx = a; piv = r; }
        }
        if (piv != c) {
            for (int cc = c; cc <= 7; cc++) {
                float t = H[c][cc]; H[c][cc] = H[piv][cc]; H[piv][cc] = t;
            }
        }
        float inv = 1.0f / H[c][c];
        for (int r = c + 1; r < np; r++) {
            float f = H[r][c] * inv;
            for (int cc = c; cc <= 7; cc++) H[r][cc] -= f * H[c][cc];
        }
    }
    float sol[7];
    for (int c = np - 1; c >= 0; c--) {
        float s = H[c][7];
        for (int cc = c + 1; cc < np; cc++) s -= H[c][cc] * sol[cc];
        sol[c] = s / H[c][c];
    }
    for (int i = 0; i < n; i++) alpha[(size_t)b * MS + i] = sol[i + 1];
}

// ---------------------------------------------------------------------------
// xnew = sum_i alpha_i F[:,i] -> X[:,up] (f32) + split-bf16 GEMM input
// also zeros dots for the next gemm; writes `result` on the final iteration
// ---------------------------------------------------------------------------
__global__ __launch_bounds__(256) void xnew_kernel(
    const float* __restrict__ F, const float* __restrict__ alpha,
    float* __restrict__ Xout, __bf16* __restrict__ Ahi, __bf16* __restrict__ Alo,
    float* __restrict__ dots, float* __restrict__ resultOrNull,
    int n, int up)
{
    int idx = blockIdx.x * 256 + threadIdx.x;
    if (idx < BSZ * MS) dots[idx] = 0.0f;
    int b = idx >> 11;
    int j = idx & (DIM - 1);
    const float* al = alpha + (size_t)b * MS;
    const float* fb = F + (size_t)b * XROWS;
    float s = 0.0f;
    for (int i = 0; i < n; i++) s = fmaf(al[i], fb[i * DIM + j], s);
    Xout[(size_t)b * XROWS + (size_t)up * DIM + j] = s;
    if (resultOrNull) resultOrNull[idx] = s;
    __bf16 h = (__bf16)s;
    Ahi[idx] = h;
    Alo[idx] = (__bf16)(s - (float)h);
}

__global__ void finalize_kernel(const float* __restrict__ norms,
                                float* __restrict__ rel, float* __restrict__ absd)
{
    int t = threadIdx.x;
    if (t < NIT) {
        float a = sqrtf(norms[2 * t]);
        float fn = sqrtf(norms[2 * t + 1]);
        absd[t] = a;
        rel[t] = a / (1e-5f + fn);
    }
}

extern "C" void kernel_launch(void* const* d_in, const int* in_sizes, int n_in,
                              void* d_out, int out_size, void* d_ws, size_t ws_size,
                              hipStream_t stream) {
    const float* x0   = (const float*)d_in[0];
    const float* W    = (const float*)d_in[1];
    const float* bias = (const float*)d_in[2];

    float* out    = (float*)d_out;
    float* result = out;
    float* Xout   = out + (size_t)BSZ * DIM;
    float* rel    = Xout + (size_t)BSZ * MS * DIM;
    float* absd   = rel + NIT;

    char* ws = (char*)d_ws;
    float* F     = (float*)ws;                                   // 100.66 MB
    float* alpha = F + (size_t)BSZ * MS * DIM;                   // 48 KB
    float* norms = alpha + (size_t)BSZ * MS;                     // 232 B
    float* dots  = norms + 64;                                   // 48 KB
    float* GGt   = dots + (size_t)BSZ * MS;                      // 288 KB
    char* p = (char*)(GGt + (size_t)BSZ * 36);
    size_t off = ((size_t)(p - ws) + 255) & ~(size_t)255;
    __bf16* Ahi  = (__bf16*)(ws + off);  off += (size_t)BSZ * DIM * 2;
    __bf16* Alo  = (__bf16*)(ws + off);  off += (size_t)BSZ * DIM * 2;
    __bf16* WThi = (__bf16*)(ws + off);  off += (size_t)DIM * DIM * 2;
    __bf16* WTlo = (__bf16*)(ws + off);

    dim3 ggrid(16, 16);

    wt_split_kernel<<<dim3(64, 64), 256, 0, stream>>>(W, WThi, WTlo);
    init_kernel<<<2048, 256, 0, stream>>>(x0, Xout, Ahi, Alo, norms, dots);
    // F[:,0] = f(x0); dots(slot0 vs slot0) for the k=1 solve
    gemm_mfma_kernel<<<ggrid, 256, 0, stream>>>(Ahi, Alo, WThi, WTlo, bias,
                                                F, Xout, 0, 1, dots, nullptr, 0);
    for (int k = 1; k <= NIT; k++) {
        int n = (k < MS) ? k : MS;
        int up = k % MS;
        int prevUp = (k - 1) % MS;
        int nact = (k + 1 < MS) ? (k + 1) : MS;
        solve_kernel<<<BSZ / 256, 256, 0, stream>>>(GGt, dots, alpha, n, prevUp);
        xnew_kernel<<<BSZ * DIM / 256, 256, 0, stream>>>(F, alpha, Xout, Ahi, Alo,
                                                         dots,
                                                         (k == NIT) ? result : nullptr,
                                                         n, up);
        gemm_mfma_kernel<<<ggrid, 256, 0, stream>>>(Ahi, Alo, WThi, WTlo, bias,
                                                    F, Xout, up, nact,
                                                    dots, norms + 2 * (k - 1), 1);
    }
    finalize_kernel<<<1, 64, 0, stream>>>(norms, rel, absd);
}

// Round 4
// 5492.009 us; speedup vs baseline: 1.1052x; 1.1052x over previous
//
#include <hip/hip_runtime.h>
#include <math.h>

#define BSZ 2048
#define DIM 2048
#define MS 6
#define NIT 29          // k = 1..29
#define LAMREG 1e-4f
#define XROWS (MS*DIM)  // 12288: row stride of the (bsz, 6, d) layouts

typedef __bf16 bf16x8 __attribute__((ext_vector_type(8)));
typedef float  f32x4  __attribute__((ext_vector_type(4)));

__device__ __forceinline__ void async16(const void* g, void* l) {
    __builtin_amdgcn_global_load_lds((const __attribute__((address_space(1))) void*)g,
                                     (__attribute__((address_space(3))) void*)l, 16, 0, 0);
}

// swizzled LDS element offset for 16B chunk q (0..3) of row r in a [128][32] bf16 panel
__device__ __forceinline__ int swz(int r, int q) {
    return r * 32 + ((q ^ ((r >> 1) & 3)) << 3);
}

// ---------------------------------------------------------------------------
// init: X[:,0] = x0, split-bf16 copy of x0, zero norms
// ---------------------------------------------------------------------------
__global__ __launch_bounds__(256) void init_kernel(const float* __restrict__ x0,
                                                   float* __restrict__ Xout,
                                                   __bf16* __restrict__ Ahi,
                                                   __bf16* __restrict__ Alo,
                                                   float* __restrict__ norms) {
    int idx = blockIdx.x * 256 + threadIdx.x;
    if (idx < 2 * NIT) norms[idx] = 0.0f;
    for (int i = idx; i < BSZ * DIM; i += gridDim.x * 256) {
        int b = i >> 11;
        int j = i & (DIM - 1);
        float v = x0[i];
        Xout[(size_t)b * XROWS + j] = v;
        __bf16 h = (__bf16)v;
        Ahi[i] = h;
        Alo[i] = (__bf16)(v - (float)h);
    }
}

// ---------------------------------------------------------------------------
// W (K x N, f32) -> W^T split into bf16 hi/lo:  WT[n][k] = W[k][n]
// ---------------------------------------------------------------------------
__global__ __launch_bounds__(256) void wt_split_kernel(const float* __restrict__ W,
                                                       __bf16* __restrict__ WThi,
                                                       __bf16* __restrict__ WTlo) {
    __shared__ float tile[32][33];
    const int tx = threadIdx.x & 31;
    const int ty = threadIdx.x >> 5;
    const int n0 = blockIdx.x * 32;
    const int k0 = blockIdx.y * 32;
#pragma unroll
    for (int i = 0; i < 32; i += 8)
        tile[ty + i][tx] = W[(size_t)(k0 + ty + i) * DIM + n0 + tx];
    __syncthreads();
#pragma unroll
    for (int i = 0; i < 32; i += 8) {
        float v = tile[tx][ty + i];
        __bf16 h = (__bf16)v;
        size_t o = (size_t)(n0 + ty + i) * DIM + k0 + tx;
        WThi[o] = h;
        WTlo[o] = (__bf16)(v - (float)h);
    }
}

// ---------------------------------------------------------------------------
// split-bf16 MFMA GEMM, double-buffered swizzled LDS, XCD-aware tile swizzle.
// Epilogue: F[:,up] = tanh(xnew@W + b); G[:,up] = f - x (if G != null);
// optional ||g||^2, ||f||^2 accumulation.
// ---------------------------------------------------------------------------
__global__ __launch_bounds__(256) void gemm_mfma_kernel(
    const __bf16* __restrict__ Ahi, const __bf16* __restrict__ Alo,
    const __bf16* __restrict__ WThi, const __bf16* __restrict__ WTlo,
    const float* __restrict__ bias,
    const float* __restrict__ Xbase, float* __restrict__ Fbase,
    float* __restrict__ Gbase, int up,
    float* __restrict__ normAcc, int doNorm)
{
    __shared__ __align__(16) __bf16 Ah[2][128 * 32];
    __shared__ __align__(16) __bf16 Al[2][128 * 32];
    __shared__ __align__(16) __bf16 Bh[2][128 * 32];
    __shared__ __align__(16) __bf16 Bl[2][128 * 32];
    __shared__ float rs[8];

    // XCD-aware swizzle: assume XCD = blockIdx.x % 8; give each XCD a 4x8
    // rectangle of the 16x16 tile grid -> its L2 holds 4 A-panels + 8 B-panels.
    const int id = blockIdx.x;
    const int xcd = id & 7;
    const int slot = id >> 3;                 // 0..31
    const int by = ((xcd & 3) << 2) | (slot & 3);
    const int bx = ((xcd >> 2) << 3) | (slot >> 2);
    const int m0 = by * 128;
    const int n0 = bx * 128;

    const int tid = threadIdx.x;
    const int l = tid & 63;
    const int w = tid >> 6;
    const int wm = (w & 1) * 64;
    const int wn = (w >> 1) * 64;
    const int rl = l & 15;
    const int quad = l >> 4;

    // staging: lane l of wave w covers row w*16 + (l>>2) (+64 for group 1),
    // LDS chunk position (l&3); load the XOR-swizzled global chunk so that
    // LDS position (row, c) holds global chunk c ^ ((row>>1)&3).
    const int srow = w * 16 + (l >> 2);
    const int gchunk = (l & 3) ^ ((l >> 3) & 3);
    const int scol = gchunk << 3;
    const size_t aoff = (size_t)(m0 + srow) * DIM + scol;
    const size_t boff = (size_t)(n0 + srow) * DIM + scol;
    const int lo = w * 512;

    f32x4 acc[4][4];
#pragma unroll
    for (int t = 0; t < 4; t++)
#pragma unroll
        for (int u = 0; u < 4; u++) acc[t][u] = (f32x4){0.f, 0.f, 0.f, 0.f};

    auto stage = [&](int kb, int s) {
        async16(Ahi + aoff + kb, &Ah[s][lo]);
        async16(Ahi + aoff + (size_t)64 * DIM + kb, &Ah[s][lo + 2048]);
        async16(Alo + aoff + kb, &Al[s][lo]);
        async16(Alo + aoff + (size_t)64 * DIM + kb, &Al[s][lo + 2048]);
        async16(WThi + boff + kb, &Bh[s][lo]);
        async16(WThi + boff + (size_t)64 * DIM + kb, &Bh[s][lo + 2048]);
        async16(WTlo + boff + kb, &Bl[s][lo]);
        async16(WTlo + boff + (size_t)64 * DIM + kb, &Bl[s][lo + 2048]);
    };
    auto compute = [&](int s) {
        bf16x8 ah[4], al[4];
#pragma unroll
        for (int t = 0; t < 4; t++) {
            const int r = wm + t * 16 + rl;
            ah[t] = *(const bf16x8*)&Ah[s][swz(r, quad)];
            al[t] = *(const bf16x8*)&Al[s][swz(r, quad)];
        }
#pragma unroll
        for (int u = 0; u < 4; u++) {
            const int c = wn + u * 16 + rl;
            bf16x8 bh = *(const bf16x8*)&Bh[s][swz(c, quad)];
            bf16x8 bl = *(const bf16x8*)&Bl[s][swz(c, quad)];
#pragma unroll
            for (int t = 0; t < 4; t++) {
                acc[t][u] = __builtin_amdgcn_mfma_f32_16x16x32_bf16(ah[t], bh, acc[t][u], 0, 0, 0);
                acc[t][u] = __builtin_amdgcn_mfma_f32_16x16x32_bf16(al[t], bh, acc[t][u], 0, 0, 0);
                acc[t][u] = __builtin_amdgcn_mfma_f32_16x16x32_bf16(ah[t], bl, acc[t][u], 0, 0, 0);
            }
        }
    };

    stage(0, 0);
    for (int k0 = 0; k0 < DIM; k0 += 64) {
        __syncthreads();               // drains buf0 loads (issued one phase ago)
        stage(k0 + 32, 1);
        compute(0);
        __syncthreads();               // drains buf1 loads
        if (k0 + 64 < DIM) stage(k0 + 64, 0);
        compute(1);
    }

    // -------------------- epilogue --------------------
    int cols[4]; float bv[4];
#pragma unroll
    for (int u = 0; u < 4; u++) {
        cols[u] = n0 + wn + u * 16 + rl;
        bv[u] = bias[cols[u]];
    }
    float s1 = 0.0f, s2 = 0.0f;
#pragma unroll
    for (int t = 0; t < 4; t++) {
#pragma unroll
        for (int r = 0; r < 4; r++) {
            const int row = m0 + wm + t * 16 + quad * 4 + r;
            const size_t base = (size_t)row * XROWS + (size_t)up * DIM;
#pragma unroll
            for (int u = 0; u < 4; u++) {
                float v = tanhf(acc[t][u][r] + bv[u]);
                float xv = Xbase[base + cols[u]];
                float g = v - xv;
                Fbase[base + cols[u]] = v;
                if (Gbase) Gbase[base + cols[u]] = g;
                if (doNorm) { s1 = fmaf(g, g, s1); s2 = fmaf(v, v, s2); }
            }
        }
    }
    if (doNorm) {
#pragma unroll
        for (int off = 32; off > 0; off >>= 1) {
            s1 += __shfl_down(s1, off);
            s2 += __shfl_down(s2, off);
        }
        if (l == 0) { rs[w * 2] = s1; rs[w * 2 + 1] = s2; }
        __syncthreads();
        if (tid == 0) {
            atomicAdd(&normAcc[0], rs[0] + rs[2] + rs[4] + rs[6]);
            atomicAdd(&normAcc[1], rs[1] + rs[3] + rs[5] + rs[7]);
        }
    }
}

// ---------------------------------------------------------------------------
// incremental Gram row: dots[b][j] = g_up . g_j  for j < nact
// one block per batch row; reads G (or recomputes g = F - X if G == null)
// ---------------------------------------------------------------------------
__global__ __launch_bounds__(256) void dots_kernel(
    const float* __restrict__ F, const float* __restrict__ X,
    const float* __restrict__ G, float* __restrict__ dots, int up, int nact)
{
    const int b = blockIdx.x;
    const int tid = threadIdx.x;
    const size_t rb = (size_t)b * XROWS;
    float acc[MS];
#pragma unroll
    for (int p = 0; p < MS; p++) acc[p] = 0.0f;

    for (int pos = tid; pos < DIM; pos += 256) {
        if (G) {
            float gu = G[rb + (size_t)up * DIM + pos];
            for (int j = 0; j < nact; j++) {
                float gj = (j == up) ? gu : G[rb + (size_t)j * DIM + pos];
                acc[j] = fmaf(gu, gj, acc[j]);
            }
        } else {
            float gu = F[rb + (size_t)up * DIM + pos] - X[rb + (size_t)up * DIM + pos];
            for (int j = 0; j < nact; j++) {
                float gj = (j == up) ? gu
                         : F[rb + (size_t)j * DIM + pos] - X[rb + (size_t)j * DIM + pos];
                acc[j] = fmaf(gu, gj, acc[j]);
            }
        }
    }
#pragma unroll
    for (int p = 0; p < MS; p++) {
        float v = acc[p];
#pragma unroll
        for (int off = 32; off > 0; off >>= 1) v += __shfl_down(v, off);
        acc[p] = v;
    }
    __shared__ float red[4][MS];
    int lane = tid & 63, wave = tid >> 6;
    if (lane == 0) {
#pragma unroll
        for (int p = 0; p < MS; p++) red[wave][p] = acc[p];
    }
    __syncthreads();
    if (tid < nact)
        dots[(size_t)b * MS + tid] = red[0][tid] + red[1][tid] + red[2][tid] + red[3][tid];
}

// ---------------------------------------------------------------------------
// per-batch: fold dots into persistent GGt (row/col prevUp), solve bordered
// (n+1) system -> alpha. One thread per batch row.
// ---------------------------------------------------------------------------
__global__ __launch_bounds__(256) void solve_kernel(
    float* __restrict__ GGt, const float* __restrict__ dots,
    float* __restrict__ alpha, int n, int prevUp)
{
    __shared__ float Hsh[256][7][8];
    const int b = blockIdx.x * 256 + threadIdx.x;
    if (b >= BSZ) return;
    float (*H)[8] = Hsh[threadIdx.x];
    float* gg = GGt + (size_t)b * 36;
    const float* dt = dots + (size_t)b * MS;
    for (int j = 0; j < n; j++) {
        float v = dt[j];
        gg[prevUp * 6 + j] = v;
        gg[j * 6 + prevUp] = v;
    }
    const int np = n + 1;
    for (int i = 0; i < np; i++) {
        for (int j = 0; j < np; j++) {
            float v;
            if (i == 0 && j == 0) v = 0.0f;
            else if (i == 0 || j == 0) v = 1.0f;
            else {
                v = gg[(i - 1) * 6 + (j - 1)];
                if (i == j) v += LAMREG;
            }
            H[i][j] = v;
        }
        H[i][7] = (i == 0) ? 1.0f : 0.0f;
    }
    for (int c = 0; c < np; c++) {
        int piv = c;
        float mx = fabsf(H[c][c]);
        for (int r = c + 1; r < np; r++) {
            float a = fabsf(H[r][c]);
            if (a > mx) { mx = a; piv = r; }
        }
        if (piv != c) {
            for (int cc = c; cc <= 7; cc++) {
                float t = H[c][cc]; H[c][cc] = H[piv][cc]; H[piv][cc] = t;
            }
        }
        float inv = 1.0f / H[c][c];
        for (int r = c + 1; r < np; r++) {
            float f = H[r][c] * inv;
            for (int cc = c; cc <= 7; cc++) H[r][cc] -= f * H[c][cc];
        }
    }
    float sol[7];
    for (int c = np - 1; c >= 0; c--) {
        float s = H[c][7];
        for (int cc = c + 1; cc < np; cc++) s -= H[c][cc] * sol[cc];
        sol[c] = s / H[c][c];
    }
    for (int i = 0; i < n; i++) alpha[(size_t)b * MS + i] = sol[i + 1];
}

// ---------------------------------------------------------------------------
// xnew = sum_i alpha_i F[:,i] -> X[:,up] (f32) + split-bf16 GEMM input
// writes `result` on the final iteration
// ---------------------------------------------------------------------------
__global__ __launch_bounds__(256) void xnew_kernel(
    const float* __restrict__ F, const float* __restrict__ alpha,
    float* __restrict__ Xout, __bf16* __restrict__ Ahi, __bf16* __restrict__ Alo,
    float* __restrict__ resultOrNull, int n, int up)
{
    int idx = blockIdx.x * 256 + threadIdx.x;
    int b = idx >> 11;
    int j = idx & (DIM - 1);
    const float* al = alpha + (size_t)b * MS;
    const float* fb = F + (size_t)b * XROWS;
    float s = 0.0f;
    for (int i = 0; i < n; i++) s = fmaf(al[i], fb[i * DIM + j], s);
    Xout[(size_t)b * XROWS + (size_t)up * DIM + j] = s;
    if (resultOrNull) resultOrNull[idx] = s;
    __bf16 h = (__bf16)s;
    Ahi[idx] = h;
    Alo[idx] = (__bf16)(s - (float)h);
}

__global__ void finalize_kernel(const float* __restrict__ norms,
                                float* __restrict__ rel, float* __restrict__ absd)
{
    int t = threadIdx.x;
    if (t < NIT) {
        float a = sqrtf(norms[2 * t]);
        float fn = sqrtf(norms[2 * t + 1]);
        absd[t] = a;
        rel[t] = a / (1e-5f + fn);
    }
}

extern "C" void kernel_launch(void* const* d_in, const int* in_sizes, int n_in,
                              void* d_out, int out_size, void* d_ws, size_t ws_size,
                              hipStream_t stream) {
    const float* x0   = (const float*)d_in[0];
    const float* W    = (const float*)d_in[1];
    const float* bias = (const float*)d_in[2];

    float* out    = (float*)d_out;
    float* result = out;
    float* Xout   = out + (size_t)BSZ * DIM;
    float* rel    = Xout + (size_t)BSZ * MS * DIM;
    float* absd   = rel + NIT;

    char* ws = (char*)d_ws;
    float* F     = (float*)ws;                                   // 100.66 MB
    float* alpha = F + (size_t)BSZ * MS * DIM;                   // 48 KB
    float* norms = alpha + (size_t)BSZ * MS;                     // 256 B
    float* dots  = norms + 64;                                   // 48 KB
    float* GGt   = dots + (size_t)BSZ * MS;                      // 288 KB
    char* p = (char*)(GGt + (size_t)BSZ * 36);
    size_t off = ((size_t)(p - ws) + 255) & ~(size_t)255;
    __bf16* Ahi  = (__bf16*)(ws + off);  off += (size_t)BSZ * DIM * 2;
    __bf16* Alo  = (__bf16*)(ws + off);  off += (size_t)BSZ * DIM * 2;
    __bf16* WThi = (__bf16*)(ws + off);  off += (size_t)DIM * DIM * 2;
    __bf16* WTlo = (__bf16*)(ws + off);  off += (size_t)DIM * DIM * 2;
    // G array (100.66 MB) only if scratch is big enough
    float* G = nullptr;
    if (ws_size >= off + (size_t)BSZ * MS * DIM * 4 + 256) {
        off = (off + 255) & ~(size_t)255;
        G = (float*)(ws + off);
    }

    wt_split_kernel<<<dim3(64, 64), 256, 0, stream>>>(W, WThi, WTlo);
    init_kernel<<<2048, 256, 0, stream>>>(x0, Xout, Ahi, Alo, norms);
    // F[:,0] = f(x0), G[:,0] = f - x0
    gemm_mfma_kernel<<<256, 256, 0, stream>>>(Ahi, Alo, WThi, WTlo, bias,
                                              Xout, F, G, 0, nullptr, 0);
    dots_kernel<<<BSZ, 256, 0, stream>>>(F, Xout, G, dots, 0, 1);
    for (int k = 1; k <= NIT; k++) {
        int n = (k < MS) ? k : MS;
        int up = k % MS;
        int prevUp = (k - 1) % MS;
        int nact = (k + 1 < MS) ? (k + 1) : MS;
        solve_kernel<<<BSZ / 256, 256, 0, stream>>>(GGt, dots, alpha, n, prevUp);
        xnew_kernel<<<BSZ * DIM / 256, 256, 0, stream>>>(F, alpha, Xout, Ahi, Alo,
                                                         (k == NIT) ? result : nullptr,
                                                         n, up);
        gemm_mfma_kernel<<<256, 256, 0, stream>>>(Ahi, Alo, WThi, WTlo, bias,
                                                  Xout, F, G, up,
                                                  norms + 2 * (k - 1), 1);
        if (k < NIT)
            dots_kernel<<<BSZ, 256, 0, stream>>>(F, Xout, G, dots, up, nact);
    }
    finalize_kernel<<<1, 64, 0, stream>>>(norms, rel, absd);
}